// Round 1
// baseline (399.828 us; speedup 1.0000x reference)
//
#include <hip/hip_runtime.h>
#include <hip/hip_bf16.h>
#include <stdint.h>

#define HEADS 16
#define DIMH 64
#define SEGL 512
#define NPM 16
#define NB 2
#define NS 4096
#define ND 1024
#define NW 8
#define NBW 16
#define KVLEN 528
#define NQKV 3072
#define MROWS 8192
#define RMS_EPS 1.1920928955078125e-07f

typedef __attribute__((ext_vector_type(8))) short bf16x8;
typedef __attribute__((ext_vector_type(4))) float f32x4;

union FragU { bf16x8 v; uint64_t q[2]; };

__device__ inline unsigned short f2bf(float x){
  __hip_bfloat16 b = __float2bfloat16(x);
  return __builtin_bit_cast(unsigned short, b);
}

__device__ inline f32x4 mfma16(bf16x8 a, bf16x8 b, f32x4 c){
  return __builtin_amdgcn_mfma_f32_16x16x32_bf16(a, b, c, 0, 0, 0);
}

// ---------------- rope table ----------------
__global__ void rope_table_k(float* __restrict__ cosT, float* __restrict__ sinT){
  int id = blockIdx.x*256 + threadIdx.x;
  if (id >= NS*32) return;
  int p = id & 31, s = id >> 5;
  float inv = powf(10000.0f, -(float)p * (1.0f/32.0f));
  float a = (float)s * inv;
  cosT[id] = cosf(a);
  sinT[id] = sinf(a);
}

// ---------------- rmsnorm + cast ----------------
__global__ __launch_bounds__(256) void rmsnorm_k(const float* __restrict__ seq, const float* __restrict__ nw,
                                                 unsigned short* __restrict__ xo){
  int r = blockIdx.x, t = threadIdx.x;
  const float4 v = ((const float4*)(seq + (size_t)r*ND))[t];
  float ss = v.x*v.x + v.y*v.y + v.z*v.z + v.w*v.w;
  #pragma unroll
  for (int off=32; off; off>>=1) ss += __shfl_xor(ss, off);
  __shared__ float red[4];
  if ((t&63)==0) red[t>>6] = ss;
  __syncthreads();
  float scale = rsqrtf((red[0]+red[1]+red[2]+red[3])*(1.0f/(float)ND) + RMS_EPS);
  const float4 w = ((const float4*)nw)[t];
  ushort4 o;
  o.x = f2bf(v.x*scale*w.x);
  o.y = f2bf(v.y*scale*w.y);
  o.z = f2bf(v.z*scale*w.z);
  o.w = f2bf(v.w*scale*w.w);
  ((ushort4*)xo)[(size_t)r*256 + t] = o;
}

// ---------------- transpose + cast weights ----------------
__global__ __launch_bounds__(256) void tcast_k(const float* __restrict__ in, unsigned short* __restrict__ out,
                                               int R, int C){
  __shared__ float tile[32][33];
  int c0 = blockIdx.x*32, r0 = blockIdx.y*32;
  int tx = threadIdx.x & 31, ty = threadIdx.x >> 5;
  #pragma unroll
  for (int i=0;i<4;i++) tile[ty+8*i][tx] = in[(size_t)(r0+ty+8*i)*C + c0+tx];
  __syncthreads();
  #pragma unroll
  for (int i=0;i<4;i++) out[(size_t)(c0+ty+8*i)*R + r0+tx] = f2bf(tile[tx][ty+8*i]);
}

// ---------------- pmem prefix fill ----------------
__global__ void pmem_fill_k(const float* __restrict__ pmem, unsigned short* __restrict__ Kb,
                            unsigned short* __restrict__ Vb){
  int id = blockIdx.x*256 + threadIdx.x;
  if (id >= NBW*HEADS*NPM*DIMH) return;
  int d = id & 63, j = (id>>6)&15, h = (id>>10)&15, bw = id>>14;
  size_t dst = ((size_t)(bw*HEADS+h)*KVLEN + j)*DIMH + d;
  size_t srcK = ((size_t)h*NPM + j)*DIMH + d;
  Kb[dst] = f2bf(pmem[srcK]);
  Vb[dst] = f2bf(pmem[(size_t)HEADS*NPM*DIMH + srcK]);
}

// ---------------- GEMM: C[M][N] = A[M][K] * Bt[N][K]^T ----------------
// MODE 0: write f32 C to Cf. MODE 1: fused qkv epilogue (rope + scatter + orig_v).
template<int MODE>
__global__ __launch_bounds__(256) void gemm_k(const unsigned short* __restrict__ A,
    const unsigned short* __restrict__ Bt, float* __restrict__ Cf,
    unsigned short* __restrict__ Qb, unsigned short* __restrict__ Kb, unsigned short* __restrict__ Vb,
    float* __restrict__ origv, const float* __restrict__ cosT, const float* __restrict__ sinT,
    int M, int N, int K){
  __shared__ __align__(16) unsigned short As[128][48];
  __shared__ __align__(16) unsigned short Bs[128][48];
  int t = threadIdx.x; int lane = t&63; int wv = t>>6; int lr = lane&15; int lg = lane>>4;
  int wm = wv>>1, wn = wv&1;
  int m0 = blockIdx.y*128, n0 = blockIdx.x*128;
  f32x4 acc[4][4];
  f32x4 z = {0.f,0.f,0.f,0.f};
  #pragma unroll
  for (int i=0;i<4;i++)
    #pragma unroll
    for (int j=0;j<4;j++) acc[i][j] = z;
  int sr = t>>2, sc = t&3;
  for (int k0=0; k0<K; k0+=32){
    __syncthreads();
    #pragma unroll
    for (int it=0; it<2; ++it){
      int r = sr + it*64;
      *(uint4*)&As[r][sc*8] = *(const uint4*)(A + (size_t)(m0+r)*K + k0 + sc*8);
      *(uint4*)&Bs[r][sc*8] = *(const uint4*)(Bt + (size_t)(n0+r)*K + k0 + sc*8);
    }
    __syncthreads();
    FragU af[4], bf[4];
    #pragma unroll
    for (int i=0;i<4;i++){
      af[i].q[0] = *(const uint64_t*)&As[wm*64+i*16+lr][lg*4];
      af[i].q[1] = *(const uint64_t*)&As[wm*64+i*16+lr][16+lg*4];
      bf[i].q[0] = *(const uint64_t*)&Bs[wn*64+i*16+lr][lg*4];
      bf[i].q[1] = *(const uint64_t*)&Bs[wn*64+i*16+lr][16+lg*4];
    }
    #pragma unroll
    for (int i=0;i<4;i++)
      #pragma unroll
      for (int j=0;j<4;j++)
        acc[i][j] = mfma16(af[i].v, bf[j].v, acc[i][j]);
  }
  #pragma unroll
  for (int i=0;i<4;i++){
    #pragma unroll
    for (int j=0;j<4;j++){
      #pragma unroll
      for (int e=0;e<4;e++){
        int row = m0 + wm*64 + i*16 + lg*4 + e;
        int col = n0 + wn*64 + j*16 + lr;
        float val = acc[i][j][e];
        if constexpr (MODE == 0){
          Cf[(size_t)row*N + col] = val;
        } else {
          float partner = __shfl_xor(val, 1);
          int b = row>>12, s = row&4095;
          int w = s>>9, ii = s&511, bw = b*8+w;
          int hh = (col>>6)&15, dh = col&63;
          if (col < 2048){
            int fp = dh>>1;
            float cs = cosT[s*32+fp], sn = sinT[s*32+fp];
            float rot = (col&1) ? fmaf(val,cs, partner*sn) : fmaf(val,cs, -partner*sn);
            if (col < 1024) Qb[((size_t)(bw*HEADS+hh)*SEGL + ii)*DIMH + dh] = f2bf(rot);
            else            Kb[((size_t)(bw*HEADS+hh)*KVLEN + NPM + ii)*DIMH + dh] = f2bf(rot);
          } else {
            Vb[((size_t)(bw*HEADS+hh)*KVLEN + NPM + ii)*DIMH + dh] = f2bf(val);
            origv[((size_t)(b*HEADS+hh)*NS + s)*DIMH + dh] = val;
          }
        }
      }
    }
  }
}

// ---------------- attention ----------------
__global__ __launch_bounds__(256) void attn_k(const unsigned short* __restrict__ Qb,
    const unsigned short* __restrict__ Kb, const unsigned short* __restrict__ Vb,
    unsigned short* __restrict__ att){
  int qt = blockIdx.x, h = blockIdx.y, bw = blockIdx.z;
  int t = threadIdx.x, lane = t&63, wv = t>>6, lr = lane&15, lg = lane>>4;
  __shared__ __align__(16) unsigned short Ks[64][80];
  __shared__ __align__(16) unsigned short Vt[64][80];
  __shared__ __align__(16) unsigned short Pl[4][16][80];
  const unsigned short* Qrow = Qb + ((size_t)((bw*HEADS+h)*SEGL) + qt*64 + wv*16 + lr)*DIMH;
  FragU qf[2];
  qf[0].q[0] = *(const uint64_t*)(Qrow + lg*4);
  qf[0].q[1] = *(const uint64_t*)(Qrow + 16 + lg*4);
  qf[1].q[0] = *(const uint64_t*)(Qrow + 32 + lg*4);
  qf[1].q[1] = *(const uint64_t*)(Qrow + 48 + lg*4);
  f32x4 o[4];
  f32x4 z = {0.f,0.f,0.f,0.f};
  #pragma unroll
  for (int d=0;d<4;d++) o[d] = z;
  const float NEG = -3.0e38f;
  float m[4], l[4];
  #pragma unroll
  for (int e=0;e<4;e++){ m[e]=NEG; l[e]=0.f; }
  const unsigned short* Kbase = Kb + (size_t)(bw*HEADS+h)*KVLEN*DIMH;
  const unsigned short* Vbase = Vb + (size_t)(bw*HEADS+h)*KVLEN*DIMH;
  int ntiles = (qt*64 + 143)>>6; if (ntiles>9) ntiles=9;
  int qrow_base = qt*64 + wv*16 + lg*4;
  for (int jt=0; jt<ntiles; ++jt){
    int j0 = jt*64;
    __syncthreads();
    #pragma unroll
    for (int it=0; it<2; ++it){
      int idx = t + it*256;
      int r = idx>>3, c = idx&7;
      int grow = j0 + r; grow = grow>527 ? 527 : grow;
      *(uint4*)&Ks[r][c*8] = *(const uint4*)(Kbase + (size_t)grow*DIMH + c*8);
      uint4 vvv = *(const uint4*)(Vbase + (size_t)grow*DIMH + c*8);
      const unsigned short* pv = (const unsigned short*)&vvv;
      #pragma unroll
      for (int e=0;e<8;e++) Vt[c*8+e][r] = pv[e];
    }
    __syncthreads();
    f32x4 s4[4];
    #pragma unroll
    for (int tn=0; tn<4; ++tn){
      f32x4 a = z;
      #pragma unroll
      for (int kh=0; kh<2; ++kh){
        FragU kf;
        kf.q[0] = *(const uint64_t*)&Ks[tn*16+lr][kh*32 + lg*4];
        kf.q[1] = *(const uint64_t*)&Ks[tn*16+lr][kh*32 + 16 + lg*4];
        a = mfma16(qf[kh].v, kf.v, a);
      }
      s4[tn] = a * 0.125f;
    }
    float mt[4] = {NEG,NEG,NEG,NEG};
    #pragma unroll
    for (int tn=0; tn<4; ++tn){
      int col = j0 + tn*16 + lr;
      bool okc = (col < KVLEN);
      #pragma unroll
      for (int e=0;e<4;e++){
        bool ok = okc && ((col - NPM) <= (qrow_base + e));
        float v = ok ? s4[tn][e] : NEG;
        s4[tn][e] = v;
        mt[e] = fmaxf(mt[e], v);
      }
    }
    #pragma unroll
    for (int off=1; off<16; off<<=1){
      #pragma unroll
      for (int e=0;e<4;e++) mt[e] = fmaxf(mt[e], __shfl_xor(mt[e], off));
    }
    float alpha[4];
    #pragma unroll
    for (int e=0;e<4;e++){
      float mn = fmaxf(m[e], mt[e]);
      alpha[e] = __expf(m[e]-mn);
      m[e] = mn;
    }
    float ps[4] = {0.f,0.f,0.f,0.f};
    #pragma unroll
    for (int tn=0; tn<4; ++tn){
      #pragma unroll
      for (int e=0;e<4;e++){
        float p = __expf(s4[tn][e] - m[e]);
        s4[tn][e] = p;
        ps[e] += p;
      }
    }
    #pragma unroll
    for (int off=1; off<16; off<<=1){
      #pragma unroll
      for (int e=0;e<4;e++) ps[e] += __shfl_xor(ps[e], off);
    }
    #pragma unroll
    for (int e=0;e<4;e++) l[e] = l[e]*alpha[e] + ps[e];
    #pragma unroll
    for (int d=0;d<4;d++)
      #pragma unroll
      for (int e=0;e<4;e++) o[d][e] *= alpha[e];
    #pragma unroll
    for (int tn=0; tn<4; ++tn)
      #pragma unroll
      for (int e=0;e<4;e++) Pl[wv][lg*4+e][tn*16+lr] = f2bf(s4[tn][e]);
    __threadfence_block();  // order P writes before cross-lane P reads (wave-synchronous)
    #pragma unroll
    for (int kh=0; kh<2; ++kh){
      FragU pf;
      pf.q[0] = *(const uint64_t*)&Pl[wv][lr][kh*32 + lg*4];
      pf.q[1] = *(const uint64_t*)&Pl[wv][lr][kh*32 + 16 + lg*4];
      #pragma unroll
      for (int d=0; d<4; ++d){
        FragU vf;
        vf.q[0] = *(const uint64_t*)&Vt[d*16+lr][kh*32 + lg*4];
        vf.q[1] = *(const uint64_t*)&Vt[d*16+lr][kh*32 + 16 + lg*4];
        o[d] = mfma16(pf.v, vf.v, o[d]);
      }
    }
  }
  int srow = bw*SEGL + qt*64 + wv*16 + lg*4;
  #pragma unroll
  for (int e=0;e<4;e++){
    float inv = 1.0f / l[e];
    #pragma unroll
    for (int d=0;d<4;d++)
      att[(size_t)(srow+e)*1024 + h*64 + d*16 + lr] = f2bf(o[d][e]*inv);
  }
}

extern "C" void kernel_launch(void* const* d_in, const int* in_sizes, int n_in,
                              void* d_out, int out_size, void* d_ws, size_t ws_size,
                              hipStream_t stream) {
  const float* seq  = (const float*)d_in[0];
  const float* nw   = (const float*)d_in[1];
  const float* wqkv = (const float*)d_in[2];
  const float* wout = (const float*)d_in[3];
  const float* pmem = (const float*)d_in[4];
  float* out0  = (float*)d_out;
  float* origv = out0 + (size_t)MROWS*ND;

  char* ws = (char*)d_ws;
  unsigned short* xbf   = (unsigned short*)(ws + 0);          // 16,777,216
  unsigned short* wqkvT = (unsigned short*)(ws + 16777216);   //  6,291,456
  unsigned short* woutT = (unsigned short*)(ws + 23068672);   //  2,097,152
  float*          cosT  = (float*)(ws + 25165824);            //    524,288
  float*          sinT  = (float*)(ws + 25690112);            //    524,288
  unsigned short* Qb    = (unsigned short*)(ws + 26214400);   // 16,777,216
  unsigned short* Kb    = (unsigned short*)(ws + 42991616);   // 17,301,504
  unsigned short* Vb    = (unsigned short*)(ws + 60293120);   // 17,301,504
  unsigned short* att   = (unsigned short*)(ws + 77594624);   // 16,777,216  (end ~94.4 MB)

  rope_table_k<<<dim3(512), dim3(256), 0, stream>>>(cosT, sinT);
  rmsnorm_k<<<dim3(MROWS), dim3(256), 0, stream>>>(seq, nw, xbf);
  tcast_k<<<dim3(NQKV/32, 1024/32), dim3(256), 0, stream>>>(wqkv, wqkvT, 1024, NQKV);
  tcast_k<<<dim3(1024/32, 1024/32), dim3(256), 0, stream>>>(wout, woutT, 1024, 1024);
  pmem_fill_k<<<dim3(1024), dim3(256), 0, stream>>>(pmem, Kb, Vb);
  gemm_k<1><<<dim3(NQKV/128, MROWS/128), dim3(256), 0, stream>>>(
      xbf, wqkvT, nullptr, Qb, Kb, Vb, origv, cosT, sinT, MROWS, NQKV, 1024);
  attn_k<<<dim3(8, 16, 16), dim3(256), 0, stream>>>(Qb, Kb, Vb, att);
  gemm_k<0><<<dim3(1024/128, MROWS/128), dim3(256), 0, stream>>>(
      att, woutT, out0, nullptr, nullptr, nullptr, nullptr, nullptr, nullptr, MROWS, 1024, 1024);
}

// Round 2
// 330.308 us; speedup vs baseline: 1.2105x; 1.2105x over previous
//
#include <hip/hip_runtime.h>
#include <hip/hip_bf16.h>
#include <stdint.h>

#define HEADS 16
#define DIMH 64
#define SEGL 512
#define NPM 16
#define NB 2
#define NS 4096
#define ND 1024
#define NW 8
#define NBW 16
#define KVLEN 528
#define NQKV 3072
#define MROWS 8192
#define RMS_EPS 1.1920928955078125e-07f

typedef __attribute__((ext_vector_type(8))) short bf16x8;
typedef __attribute__((ext_vector_type(4))) float f32x4;

union FragU { bf16x8 v; uint64_t q[2]; };

__device__ inline unsigned short f2bf(float x){
  __hip_bfloat16 b = __float2bfloat16(x);
  return __builtin_bit_cast(unsigned short, b);
}

__device__ inline f32x4 mfma16(bf16x8 a, bf16x8 b, f32x4 c){
  return __builtin_amdgcn_mfma_f32_16x16x32_bf16(a, b, c, 0, 0, 0);
}

// async global->LDS, 16B per lane; LDS dest = wave-uniform base + lane*16
__device__ __forceinline__ void gl_lds16(const unsigned short* g, unsigned short* l){
  __builtin_amdgcn_global_load_lds(
    (const __attribute__((address_space(1))) unsigned int*)g,
    (__attribute__((address_space(3))) unsigned int*)l, 16, 0, 0);
}

// ---------------- rope table ----------------
__global__ void rope_table_k(float* __restrict__ cosT, float* __restrict__ sinT){
  int id = blockIdx.x*256 + threadIdx.x;
  if (id >= NS*32) return;
  int p = id & 31, s = id >> 5;
  float inv = powf(10000.0f, -(float)p * (1.0f/32.0f));
  float a = (float)s * inv;
  cosT[id] = cosf(a);
  sinT[id] = sinf(a);
}

// ---------------- rmsnorm + cast ----------------
__global__ __launch_bounds__(256) void rmsnorm_k(const float* __restrict__ seq, const float* __restrict__ nw,
                                                 unsigned short* __restrict__ xo){
  int r = blockIdx.x, t = threadIdx.x;
  const float4 v = ((const float4*)(seq + (size_t)r*ND))[t];
  float ss = v.x*v.x + v.y*v.y + v.z*v.z + v.w*v.w;
  #pragma unroll
  for (int off=32; off; off>>=1) ss += __shfl_xor(ss, off);
  __shared__ float red[4];
  if ((t&63)==0) red[t>>6] = ss;
  __syncthreads();
  float scale = rsqrtf((red[0]+red[1]+red[2]+red[3])*(1.0f/(float)ND) + RMS_EPS);
  const float4 w = ((const float4*)nw)[t];
  ushort4 o;
  o.x = f2bf(v.x*scale*w.x);
  o.y = f2bf(v.y*scale*w.y);
  o.z = f2bf(v.z*scale*w.z);
  o.w = f2bf(v.w*scale*w.w);
  ((ushort4*)xo)[(size_t)r*256 + t] = o;
}

// ---------------- transpose + cast weights ----------------
__global__ __launch_bounds__(256) void tcast_k(const float* __restrict__ in, unsigned short* __restrict__ out,
                                               int R, int C){
  __shared__ float tile[32][33];
  int c0 = blockIdx.x*32, r0 = blockIdx.y*32;
  int tx = threadIdx.x & 31, ty = threadIdx.x >> 5;
  #pragma unroll
  for (int i=0;i<4;i++) tile[ty+8*i][tx] = in[(size_t)(r0+ty+8*i)*C + c0+tx];
  __syncthreads();
  #pragma unroll
  for (int i=0;i<4;i++) out[(size_t)(c0+ty+8*i)*R + r0+tx] = f2bf(tile[tx][ty+8*i]);
}

// ---------------- pmem prefix fill ----------------
__global__ void pmem_fill_k(const float* __restrict__ pmem, unsigned short* __restrict__ Kb,
                            unsigned short* __restrict__ Vb){
  int id = blockIdx.x*256 + threadIdx.x;
  if (id >= NBW*HEADS*NPM*DIMH) return;
  int d = id & 63, j = (id>>6)&15, h = (id>>10)&15, bw = id>>14;
  size_t dst = ((size_t)(bw*HEADS+h)*KVLEN + j)*DIMH + d;
  size_t srcK = ((size_t)h*NPM + j)*DIMH + d;
  Kb[dst] = f2bf(pmem[srcK]);
  Vb[dst] = f2bf(pmem[(size_t)HEADS*NPM*DIMH + srcK]);
}

// ---------------- GEMM: C[M][N] = A[M][K] * Bt[N][K]^T  (m97 structure) ----------------
// LDS tiles stored LINEARLY [128][32] bf16 (64B/row), filled by global_load_lds w=16.
// MODE 0: write f32 C to Cf. MODE 1: fused qkv epilogue (rope + scatter + orig_v).
template<int MODE>
__global__ __launch_bounds__(256) void gemm_k(const unsigned short* __restrict__ A,
    const unsigned short* __restrict__ Bt, float* __restrict__ Cf,
    unsigned short* __restrict__ Qb, unsigned short* __restrict__ Kb, unsigned short* __restrict__ Vb,
    float* __restrict__ origv, const float* __restrict__ cosT, const float* __restrict__ sinT,
    int M, int N, int K){
  __shared__ __align__(16) unsigned short As[4096];  // [128][32]
  __shared__ __align__(16) unsigned short Bs[4096];  // [128][32]
  int t = threadIdx.x; int lane = t&63; int wv = t>>6; int lr = lane&15; int lg = lane>>4;
  int wm = wv>>1, wn = wv&1;
  int m0 = blockIdx.y*128, n0 = blockIdx.x*128;

  f32x4 acc[4][4];
  f32x4 z = {0.f,0.f,0.f,0.f};
  #pragma unroll
  for (int i=0;i<4;i++)
    #pragma unroll
    for (int j=0;j<4;j++) acc[i][j] = z;

  // staging: wave wv covers rows [wv*32, wv*32+32); lane l -> row wv*32+(l>>2), k-chunk (l&3)*8
  const unsigned short* gA = A  + (size_t)(m0 + wv*32 + (lane>>2))*K + (lane&3)*8;
  const unsigned short* gB = Bt + (size_t)(n0 + wv*32 + (lane>>2))*K + (lane&3)*8;
  unsigned short* lA0 = As + wv*1024;          // byte offset wv*2048
  unsigned short* lA1 = As + wv*1024 + 512;    // +1024B
  unsigned short* lB0 = Bs + wv*1024;
  unsigned short* lB1 = Bs + wv*1024 + 512;
  const size_t row16 = (size_t)16*K;

  // frag read byte offsets (linear layout: row*64 + lg*16)
  int aoff[4], boff[4];
  #pragma unroll
  for (int i=0;i<4;i++){
    aoff[i] = (wm*64 + i*16 + lr)*64 + lg*16;
    boff[i] = (wn*64 + i*16 + lr)*64 + lg*16;
  }
  const char* AsB = (const char*)As;
  const char* BsB = (const char*)Bs;

  for (int k0=0; k0<K; k0+=32){
    __syncthreads();                 // previous tile fully consumed
    gl_lds16(gA + k0,         lA0);
    gl_lds16(gA + row16 + k0, lA1);
    gl_lds16(gB + k0,         lB0);
    gl_lds16(gB + row16 + k0, lB1);
    __syncthreads();                 // vmcnt(0) drain before barrier -> tile ready
    bf16x8 af[4], bfr[4];
    #pragma unroll
    for (int i=0;i<4;i++){
      af[i]  = *(const bf16x8*)(AsB + aoff[i]);
      bfr[i] = *(const bf16x8*)(BsB + boff[i]);
    }
    #pragma unroll
    for (int i=0;i<4;i++)
      #pragma unroll
      for (int j=0;j<4;j++)
        acc[i][j] = mfma16(af[i], bfr[j], acc[i][j]);
  }

  #pragma unroll
  for (int i=0;i<4;i++){
    #pragma unroll
    for (int j=0;j<4;j++){
      #pragma unroll
      for (int e=0;e<4;e++){
        int row = m0 + wm*64 + i*16 + lg*4 + e;
        int col = n0 + wn*64 + j*16 + lr;
        float val = acc[i][j][e];
        if constexpr (MODE == 0){
          Cf[(size_t)row*N + col] = val;
        } else {
          float partner = __shfl_xor(val, 1);
          int b = row>>12, s = row&4095;
          int w = s>>9, ii = s&511, bw = b*8+w;
          int hh = (col>>6)&15, dh = col&63;
          if (col < 2048){
            int fp = dh>>1;
            float cs = cosT[s*32+fp], sn = sinT[s*32+fp];
            float rot = (col&1) ? fmaf(val,cs, partner*sn) : fmaf(val,cs, -partner*sn);
            if (col < 1024) Qb[((size_t)(bw*HEADS+hh)*SEGL + ii)*DIMH + dh] = f2bf(rot);
            else            Kb[((size_t)(bw*HEADS+hh)*KVLEN + NPM + ii)*DIMH + dh] = f2bf(rot);
          } else {
            Vb[((size_t)(bw*HEADS+hh)*KVLEN + NPM + ii)*DIMH + dh] = f2bf(val);
            origv[((size_t)(b*HEADS+hh)*NS + s)*DIMH + dh] = val;
          }
        }
      }
    }
  }
}

// ---------------- attention ----------------
__global__ __launch_bounds__(256) void attn_k(const unsigned short* __restrict__ Qb,
    const unsigned short* __restrict__ Kb, const unsigned short* __restrict__ Vb,
    unsigned short* __restrict__ att){
  int qt = blockIdx.x, h = blockIdx.y, bw = blockIdx.z;
  int t = threadIdx.x, lane = t&63, wv = t>>6, lr = lane&15, lg = lane>>4;
  __shared__ __align__(16) unsigned short Ks[64][80];
  __shared__ __align__(16) unsigned short Vt[64][80];
  __shared__ __align__(16) unsigned short Pl[4][16][80];
  const unsigned short* Qrow = Qb + ((size_t)((bw*HEADS+h)*SEGL) + qt*64 + wv*16 + lr)*DIMH;
  FragU qf[2];
  qf[0].q[0] = *(const uint64_t*)(Qrow + lg*4);
  qf[0].q[1] = *(const uint64_t*)(Qrow + 16 + lg*4);
  qf[1].q[0] = *(const uint64_t*)(Qrow + 32 + lg*4);
  qf[1].q[1] = *(const uint64_t*)(Qrow + 48 + lg*4);
  f32x4 o[4];
  f32x4 z = {0.f,0.f,0.f,0.f};
  #pragma unroll
  for (int d=0;d<4;d++) o[d] = z;
  const float NEG = -3.0e38f;
  float m[4], l[4];
  #pragma unroll
  for (int e=0;e<4;e++){ m[e]=NEG; l[e]=0.f; }
  const unsigned short* Kbase = Kb + (size_t)(bw*HEADS+h)*KVLEN*DIMH;
  const unsigned short* Vbase = Vb + (size_t)(bw*HEADS+h)*KVLEN*DIMH;
  int ntiles = (qt*64 + 143)>>6; if (ntiles>9) ntiles=9;
  int qrow_base = qt*64 + wv*16 + lg*4;
  for (int jt=0; jt<ntiles; ++jt){
    int j0 = jt*64;
    __syncthreads();
    #pragma unroll
    for (int it=0; it<2; ++it){
      int idx = t + it*256;
      int r = idx>>3, c = idx&7;
      int grow = j0 + r; grow = grow>527 ? 527 : grow;
      *(uint4*)&Ks[r][c*8] = *(const uint4*)(Kbase + (size_t)grow*DIMH + c*8);
      uint4 vvv = *(const uint4*)(Vbase + (size_t)grow*DIMH + c*8);
      const unsigned short* pv = (const unsigned short*)&vvv;
      #pragma unroll
      for (int e=0;e<8;e++) Vt[c*8+e][r] = pv[e];
    }
    __syncthreads();
    f32x4 s4[4];
    #pragma unroll
    for (int tn=0; tn<4; ++tn){
      f32x4 a = z;
      #pragma unroll
      for (int kh=0; kh<2; ++kh){
        FragU kf;
        kf.q[0] = *(const uint64_t*)&Ks[tn*16+lr][kh*32 + lg*4];
        kf.q[1] = *(const uint64_t*)&Ks[tn*16+lr][kh*32 + 16 + lg*4];
        a = mfma16(qf[kh].v, kf.v, a);
      }
      s4[tn] = a * 0.125f;
    }
    float mt[4] = {NEG,NEG,NEG,NEG};
    #pragma unroll
    for (int tn=0; tn<4; ++tn){
      int col = j0 + tn*16 + lr;
      bool okc = (col < KVLEN);
      #pragma unroll
      for (int e=0;e<4;e++){
        bool ok = okc && ((col - NPM) <= (qrow_base + e));
        float v = ok ? s4[tn][e] : NEG;
        s4[tn][e] = v;
        mt[e] = fmaxf(mt[e], v);
      }
    }
    #pragma unroll
    for (int off=1; off<16; off<<=1){
      #pragma unroll
      for (int e=0;e<4;e++) mt[e] = fmaxf(mt[e], __shfl_xor(mt[e], off));
    }
    float alpha[4];
    #pragma unroll
    for (int e=0;e<4;e++){
      float mn = fmaxf(m[e], mt[e]);
      alpha[e] = __expf(m[e]-mn);
      m[e] = mn;
    }
    float ps[4] = {0.f,0.f,0.f,0.f};
    #pragma unroll
    for (int tn=0; tn<4; ++tn){
      #pragma unroll
      for (int e=0;e<4;e++){
        float p = __expf(s4[tn][e] - m[e]);
        s4[tn][e] = p;
        ps[e] += p;
      }
    }
    #pragma unroll
    for (int off=1; off<16; off<<=1){
      #pragma unroll
      for (int e=0;e<4;e++) ps[e] += __shfl_xor(ps[e], off);
    }
    #pragma unroll
    for (int e=0;e<4;e++) l[e] = l[e]*alpha[e] + ps[e];
    #pragma unroll
    for (int d=0;d<4;d++)
      #pragma unroll
      for (int e=0;e<4;e++) o[d][e] *= alpha[e];
    #pragma unroll
    for (int tn=0; tn<4; ++tn)
      #pragma unroll
      for (int e=0;e<4;e++) Pl[wv][lg*4+e][tn*16+lr] = f2bf(s4[tn][e]);
    __threadfence_block();  // order P writes before cross-lane P reads (wave-synchronous)
    #pragma unroll
    for (int kh=0; kh<2; ++kh){
      FragU pf;
      pf.q[0] = *(const uint64_t*)&Pl[wv][lr][kh*32 + lg*4];
      pf.q[1] = *(const uint64_t*)&Pl[wv][lr][kh*32 + 16 + lg*4];
      #pragma unroll
      for (int d=0; d<4; ++d){
        FragU vf;
        vf.q[0] = *(const uint64_t*)&Vt[d*16+lr][kh*32 + lg*4];
        vf.q[1] = *(const uint64_t*)&Vt[d*16+lr][kh*32 + 16 + lg*4];
        o[d] = mfma16(pf.v, vf.v, o[d]);
      }
    }
  }
  int srow = bw*SEGL + qt*64 + wv*16 + lg*4;
  #pragma unroll
  for (int e=0;e<4;e++){
    float inv = 1.0f / l[e];
    #pragma unroll
    for (int d=0;d<4;d++)
      att[(size_t)(srow+e)*1024 + h*64 + d*16 + lr] = f2bf(o[d][e]*inv);
  }
}

extern "C" void kernel_launch(void* const* d_in, const int* in_sizes, int n_in,
                              void* d_out, int out_size, void* d_ws, size_t ws_size,
                              hipStream_t stream) {
  const float* seq  = (const float*)d_in[0];
  const float* nw   = (const float*)d_in[1];
  const float* wqkv = (const float*)d_in[2];
  const float* wout = (const float*)d_in[3];
  const float* pmem = (const float*)d_in[4];
  float* out0  = (float*)d_out;
  float* origv = out0 + (size_t)MROWS*ND;

  char* ws = (char*)d_ws;
  unsigned short* xbf   = (unsigned short*)(ws + 0);          // 16,777,216
  unsigned short* wqkvT = (unsigned short*)(ws + 16777216);   //  6,291,456
  unsigned short* woutT = (unsigned short*)(ws + 23068672);   //  2,097,152
  float*          cosT  = (float*)(ws + 25165824);            //    524,288
  float*          sinT  = (float*)(ws + 25690112);            //    524,288
  unsigned short* Qb    = (unsigned short*)(ws + 26214400);   // 16,777,216
  unsigned short* Kb    = (unsigned short*)(ws + 42991616);   // 17,301,504
  unsigned short* Vb    = (unsigned short*)(ws + 60293120);   // 17,301,504
  unsigned short* att   = (unsigned short*)(ws + 77594624);   // 16,777,216  (end ~94.4 MB)

  rope_table_k<<<dim3(512), dim3(256), 0, stream>>>(cosT, sinT);
  rmsnorm_k<<<dim3(MROWS), dim3(256), 0, stream>>>(seq, nw, xbf);
  tcast_k<<<dim3(NQKV/32, 1024/32), dim3(256), 0, stream>>>(wqkv, wqkvT, 1024, NQKV);
  tcast_k<<<dim3(1024/32, 1024/32), dim3(256), 0, stream>>>(wout, woutT, 1024, 1024);
  pmem_fill_k<<<dim3(1024), dim3(256), 0, stream>>>(pmem, Kb, Vb);
  gemm_k<1><<<dim3(NQKV/128, MROWS/128), dim3(256), 0, stream>>>(
      xbf, wqkvT, nullptr, Qb, Kb, Vb, origv, cosT, sinT, MROWS, NQKV, 1024);
  attn_k<<<dim3(8, 16, 16), dim3(256), 0, stream>>>(Qb, Kb, Vb, att);
  gemm_k<0><<<dim3(1024/128, MROWS/128), dim3(256), 0, stream>>>(
      att, woutT, out0, nullptr, nullptr, nullptr, nullptr, nullptr, nullptr, MROWS, 1024, 1024);
}

// Round 3
// 292.965 us; speedup vs baseline: 1.3648x; 1.1275x over previous
//
#include <hip/hip_runtime.h>
#include <hip/hip_bf16.h>
#include <stdint.h>

#define HEADS 16
#define DIMH 64
#define SEGL 512
#define NPM 16
#define NB 2
#define NS 4096
#define ND 1024
#define NW 8
#define NBW 16
#define KVLEN 528
#define NQKV 3072
#define MROWS 8192
#define RMS_EPS 1.1920928955078125e-07f

typedef __attribute__((ext_vector_type(8))) short bf16x8;
typedef __attribute__((ext_vector_type(4))) float f32x4;

union FragU { bf16x8 v; uint64_t q[2]; };

__device__ inline unsigned short f2bf(float x){
  __hip_bfloat16 b = __float2bfloat16(x);
  return __builtin_bit_cast(unsigned short, b);
}

__device__ inline f32x4 mfma16(bf16x8 a, bf16x8 b, f32x4 c){
  return __builtin_amdgcn_mfma_f32_16x16x32_bf16(a, b, c, 0, 0, 0);
}

// async global->LDS, 16B per lane; LDS dest = wave-uniform base + lane*16
__device__ __forceinline__ void gl_lds16(const unsigned short* g, unsigned short* l){
  __builtin_amdgcn_global_load_lds(
    (const __attribute__((address_space(1))) unsigned int*)g,
    (__attribute__((address_space(3))) unsigned int*)l, 16, 0, 0);
}

// stage one wave's 32 rows (16B/lane per inst) of A and B K-chunks
__device__ __forceinline__ void stage4(const unsigned short* gA, const unsigned short* gB,
                                       unsigned short* sA, unsigned short* sB, size_t row16){
  gl_lds16(gA,         sA);
  gl_lds16(gA + row16, sA + 512);
  gl_lds16(gB,         sB);
  gl_lds16(gB + row16, sB + 512);
}

// ---------------- rope table ----------------
__global__ void rope_table_k(float* __restrict__ cosT, float* __restrict__ sinT){
  int id = blockIdx.x*256 + threadIdx.x;
  if (id >= NS*32) return;
  int p = id & 31, s = id >> 5;
  float inv = powf(10000.0f, -(float)p * (1.0f/32.0f));
  float a = (float)s * inv;
  cosT[id] = cosf(a);
  sinT[id] = sinf(a);
}

// ---------------- rmsnorm + cast ----------------
__global__ __launch_bounds__(256) void rmsnorm_k(const float* __restrict__ seq, const float* __restrict__ nw,
                                                 unsigned short* __restrict__ xo){
  int r = blockIdx.x, t = threadIdx.x;
  const float4 v = ((const float4*)(seq + (size_t)r*ND))[t];
  float ss = v.x*v.x + v.y*v.y + v.z*v.z + v.w*v.w;
  #pragma unroll
  for (int off=32; off; off>>=1) ss += __shfl_xor(ss, off);
  __shared__ float red[4];
  if ((t&63)==0) red[t>>6] = ss;
  __syncthreads();
  float scale = rsqrtf((red[0]+red[1]+red[2]+red[3])*(1.0f/(float)ND) + RMS_EPS);
  const float4 w = ((const float4*)nw)[t];
  ushort4 o;
  o.x = f2bf(v.x*scale*w.x);
  o.y = f2bf(v.y*scale*w.y);
  o.z = f2bf(v.z*scale*w.z);
  o.w = f2bf(v.w*scale*w.w);
  ((ushort4*)xo)[(size_t)r*256 + t] = o;
}

// ---------------- transpose + cast weights ----------------
__global__ __launch_bounds__(256) void tcast_k(const float* __restrict__ in, unsigned short* __restrict__ out,
                                               int R, int C){
  __shared__ float tile[32][33];
  int c0 = blockIdx.x*32, r0 = blockIdx.y*32;
  int tx = threadIdx.x & 31, ty = threadIdx.x >> 5;
  #pragma unroll
  for (int i=0;i<4;i++) tile[ty+8*i][tx] = in[(size_t)(r0+ty+8*i)*C + c0+tx];
  __syncthreads();
  #pragma unroll
  for (int i=0;i<4;i++) out[(size_t)(c0+ty+8*i)*R + r0+tx] = f2bf(tile[tx][ty+8*i]);
}

// ---------------- pmem prefix fill ----------------
__global__ void pmem_fill_k(const float* __restrict__ pmem, unsigned short* __restrict__ Kb,
                            unsigned short* __restrict__ Vb){
  int id = blockIdx.x*256 + threadIdx.x;
  if (id >= NBW*HEADS*NPM*DIMH) return;
  int d = id & 63, j = (id>>6)&15, h = (id>>10)&15, bw = id>>14;
  size_t dst = ((size_t)(bw*HEADS+h)*KVLEN + j)*DIMH + d;
  size_t srcK = ((size_t)h*NPM + j)*DIMH + d;
  Kb[dst] = f2bf(pmem[srcK]);
  Vb[dst] = f2bf(pmem[(size_t)HEADS*NPM*DIMH + srcK]);
}

// ---------------- GEMM body: C[M][N] = A[M][K] * Bt[N][K]^T ----------------
// 128x128 tile, BK=32, double-buffered LDS, T3-minimum 2-phase schedule:
//   STAGE(next tile, buf^1) -> ds_read+MFMA(cur) -> one barrier (drains vmcnt)
// LDS tiles stored LINEARLY [128][32] bf16 (64B/row), filled by global_load_lds w=16.
// MODE 0: write f32 C to Cf. MODE 1: fused qkv epilogue (rope + scatter + orig_v).
template<int MODE>
__device__ __forceinline__ void gemm_body(const unsigned short* __restrict__ A,
    const unsigned short* __restrict__ Bt, float* __restrict__ Cf,
    unsigned short* __restrict__ Qb, unsigned short* __restrict__ Kb, unsigned short* __restrict__ Vb,
    float* __restrict__ origv, const float* __restrict__ cosT, const float* __restrict__ sinT,
    int M, int N, int K){
  __shared__ __align__(16) unsigned short As[2][4096];  // [buf][128][32]
  __shared__ __align__(16) unsigned short Bs[2][4096];
  int t = threadIdx.x; int lane = t&63; int wv = t>>6; int lr = lane&15; int lg = lane>>4;
  int wm = wv>>1, wn = wv&1;
  int m0 = blockIdx.y*128, n0 = blockIdx.x*128;

  f32x4 acc[4][4];
  f32x4 z = {0.f,0.f,0.f,0.f};
  #pragma unroll
  for (int i=0;i<4;i++)
    #pragma unroll
    for (int j=0;j<4;j++) acc[i][j] = z;

  // staging: wave wv covers rows [wv*32, wv*32+32); lane l -> row wv*32+(l>>2), k-chunk (l&3)*8
  const unsigned short* gA = A  + (size_t)(m0 + wv*32 + (lane>>2))*K + (lane&3)*8;
  const unsigned short* gB = Bt + (size_t)(n0 + wv*32 + (lane>>2))*K + (lane&3)*8;
  const size_t row16 = (size_t)16*K;

  // frag read byte offsets (linear layout: row*64B + lg*16B)
  int aoff[4], boff[4];
  #pragma unroll
  for (int i=0;i<4;i++){
    aoff[i] = (wm*64 + i*16 + lr)*64 + lg*16;
    boff[i] = (wn*64 + i*16 + lr)*64 + lg*16;
  }

  // prologue: stage tile 0 into buf 0, drain, barrier
  stage4(gA, gB, As[0] + wv*1024, Bs[0] + wv*1024, row16);
  __syncthreads();

  int cur = 0;
  for (int k0=0; k0<K; k0+=32){
    int nk = k0 + 32;
    if (nk < K)  // issue next tile's loads BEFORE consuming current (overlap)
      stage4(gA + nk, gB + nk, As[cur^1] + wv*1024, Bs[cur^1] + wv*1024, row16);
    const char* AsB = (const char*)As[cur];
    const char* BsB = (const char*)Bs[cur];
    bf16x8 af[4], bfr[4];
    #pragma unroll
    for (int i=0;i<4;i++){
      af[i]  = *(const bf16x8*)(AsB + aoff[i]);
      bfr[i] = *(const bf16x8*)(BsB + boff[i]);
    }
    #pragma unroll
    for (int i=0;i<4;i++)
      #pragma unroll
      for (int j=0;j<4;j++)
        acc[i][j] = mfma16(af[i], bfr[j], acc[i][j]);
    __syncthreads();  // drains my vmcnt (next tile landed) + all waves done reading cur
    cur ^= 1;
  }

  #pragma unroll
  for (int i=0;i<4;i++){
    #pragma unroll
    for (int j=0;j<4;j++){
      #pragma unroll
      for (int e=0;e<4;e++){
        int row = m0 + wm*64 + i*16 + lg*4 + e;
        int col = n0 + wn*64 + j*16 + lr;
        float val = acc[i][j][e];
        if constexpr (MODE == 0){
          Cf[(size_t)row*N + col] = val;
        } else {
          float partner = __shfl_xor(val, 1);
          int b = row>>12, s = row&4095;
          int w = s>>9, ii = s&511, bw = b*8+w;
          int hh = (col>>6)&15, dh = col&63;
          if (col < 2048){
            int fp = dh>>1;
            float cs = cosT[s*32+fp], sn = sinT[s*32+fp];
            float rot = (col&1) ? fmaf(val,cs, partner*sn) : fmaf(val,cs, -partner*sn);
            if (col < 1024) Qb[((size_t)(bw*HEADS+hh)*SEGL + ii)*DIMH + dh] = f2bf(rot);
            else            Kb[((size_t)(bw*HEADS+hh)*KVLEN + NPM + ii)*DIMH + dh] = f2bf(rot);
          } else {
            Vb[((size_t)(bw*HEADS+hh)*KVLEN + NPM + ii)*DIMH + dh] = f2bf(val);
            origv[((size_t)(b*HEADS+hh)*NS + s)*DIMH + dh] = val;
          }
        }
      }
    }
  }
}

__global__ __launch_bounds__(256) void gemm_qkv_k(const unsigned short* __restrict__ A,
    const unsigned short* __restrict__ Bt,
    unsigned short* __restrict__ Qb, unsigned short* __restrict__ Kb, unsigned short* __restrict__ Vb,
    float* __restrict__ origv, const float* __restrict__ cosT, const float* __restrict__ sinT){
  gemm_body<1>(A, Bt, nullptr, Qb, Kb, Vb, origv, cosT, sinT, MROWS, NQKV, 1024);
}

__global__ __launch_bounds__(256) void gemm_out_k(const unsigned short* __restrict__ A,
    const unsigned short* __restrict__ Bt, float* __restrict__ Cf){
  gemm_body<0>(A, Bt, Cf, nullptr, nullptr, nullptr, nullptr, nullptr, nullptr, MROWS, 1024, 1024);
}

// ---------------- attention ----------------
__global__ __launch_bounds__(256) void attn_k(const unsigned short* __restrict__ Qb,
    const unsigned short* __restrict__ Kb, const unsigned short* __restrict__ Vb,
    unsigned short* __restrict__ att){
  int qt = blockIdx.x, h = blockIdx.y, bw = blockIdx.z;
  int t = threadIdx.x, lane = t&63, wv = t>>6, lr = lane&15, lg = lane>>4;
  __shared__ __align__(16) unsigned short Ks[64][80];
  __shared__ __align__(16) unsigned short Vt[64][80];
  __shared__ __align__(16) unsigned short Pl[4][16][80];
  const unsigned short* Qrow = Qb + ((size_t)((bw*HEADS+h)*SEGL) + qt*64 + wv*16 + lr)*DIMH;
  FragU qf[2];
  qf[0].q[0] = *(const uint64_t*)(Qrow + lg*4);
  qf[0].q[1] = *(const uint64_t*)(Qrow + 16 + lg*4);
  qf[1].q[0] = *(const uint64_t*)(Qrow + 32 + lg*4);
  qf[1].q[1] = *(const uint64_t*)(Qrow + 48 + lg*4);
  f32x4 o[4];
  f32x4 z = {0.f,0.f,0.f,0.f};
  #pragma unroll
  for (int d=0;d<4;d++) o[d] = z;
  const float NEG = -3.0e38f;
  float m[4], l[4];
  #pragma unroll
  for (int e=0;e<4;e++){ m[e]=NEG; l[e]=0.f; }
  const unsigned short* Kbase = Kb + (size_t)(bw*HEADS+h)*KVLEN*DIMH;
  const unsigned short* Vbase = Vb + (size_t)(bw*HEADS+h)*KVLEN*DIMH;
  int ntiles = (qt*64 + 143)>>6; if (ntiles>9) ntiles=9;
  int qrow_base = qt*64 + wv*16 + lg*4;
  for (int jt=0; jt<ntiles; ++jt){
    int j0 = jt*64;
    __syncthreads();
    #pragma unroll
    for (int it=0; it<2; ++it){
      int idx = t + it*256;
      int r = idx>>3, c = idx&7;
      int grow = j0 + r; grow = grow>527 ? 527 : grow;
      *(uint4*)&Ks[r][c*8] = *(const uint4*)(Kbase + (size_t)grow*DIMH + c*8);
      uint4 vvv = *(const uint4*)(Vbase + (size_t)grow*DIMH + c*8);
      const unsigned short* pv = (const unsigned short*)&vvv;
      #pragma unroll
      for (int e=0;e<8;e++) Vt[c*8+e][r] = pv[e];
    }
    __syncthreads();
    f32x4 s4[4];
    #pragma unroll
    for (int tn=0; tn<4; ++tn){
      f32x4 a = z;
      #pragma unroll
      for (int kh=0; kh<2; ++kh){
        FragU kf;
        kf.q[0] = *(const uint64_t*)&Ks[tn*16+lr][kh*32 + lg*4];
        kf.q[1] = *(const uint64_t*)&Ks[tn*16+lr][kh*32 + 16 + lg*4];
        a = mfma16(qf[kh].v, kf.v, a);
      }
      s4[tn] = a * 0.125f;
    }
    float mt[4] = {NEG,NEG,NEG,NEG};
    #pragma unroll
    for (int tn=0; tn<4; ++tn){
      int col = j0 + tn*16 + lr;
      bool okc = (col < KVLEN);
      #pragma unroll
      for (int e=0;e<4;e++){
        bool ok = okc && ((col - NPM) <= (qrow_base + e));
        float v = ok ? s4[tn][e] : NEG;
        s4[tn][e] = v;
        mt[e] = fmaxf(mt[e], v);
      }
    }
    #pragma unroll
    for (int off=1; off<16; off<<=1){
      #pragma unroll
      for (int e=0;e<4;e++) mt[e] = fmaxf(mt[e], __shfl_xor(mt[e], off));
    }
    float alpha[4];
    #pragma unroll
    for (int e=0;e<4;e++){
      float mn = fmaxf(m[e], mt[e]);
      alpha[e] = __expf(m[e]-mn);
      m[e] = mn;
    }
    float ps[4] = {0.f,0.f,0.f,0.f};
    #pragma unroll
    for (int tn=0; tn<4; ++tn){
      #pragma unroll
      for (int e=0;e<4;e++){
        float p = __expf(s4[tn][e] - m[e]);
        s4[tn][e] = p;
        ps[e] += p;
      }
    }
    #pragma unroll
    for (int off=1; off<16; off<<=1){
      #pragma unroll
      for (int e=0;e<4;e++) ps[e] += __shfl_xor(ps[e], off);
    }
    #pragma unroll
    for (int e=0;e<4;e++) l[e] = l[e]*alpha[e] + ps[e];
    #pragma unroll
    for (int d=0;d<4;d++)
      #pragma unroll
      for (int e=0;e<4;e++) o[d][e] *= alpha[e];
    #pragma unroll
    for (int tn=0; tn<4; ++tn)
      #pragma unroll
      for (int e=0;e<4;e++) Pl[wv][lg*4+e][tn*16+lr] = f2bf(s4[tn][e]);
    __threadfence_block();  // order P writes before cross-lane P reads (wave-synchronous)
    #pragma unroll
    for (int kh=0; kh<2; ++kh){
      FragU pf;
      pf.q[0] = *(const uint64_t*)&Pl[wv][lr][kh*32 + lg*4];
      pf.q[1] = *(const uint64_t*)&Pl[wv][lr][kh*32 + 16 + lg*4];
      #pragma unroll
      for (int d=0; d<4; ++d){
        FragU vf;
        vf.q[0] = *(const uint64_t*)&Vt[d*16+lr][kh*32 + lg*4];
        vf.q[1] = *(const uint64_t*)&Vt[d*16+lr][kh*32 + 16 + lg*4];
        o[d] = mfma16(pf.v, vf.v, o[d]);
      }
    }
  }
  int srow = bw*SEGL + qt*64 + wv*16 + lg*4;
  #pragma unroll
  for (int e=0;e<4;e++){
    float inv = 1.0f / l[e];
    #pragma unroll
    for (int d=0;d<4;d++)
      att[(size_t)(srow+e)*1024 + h*64 + d*16 + lr] = f2bf(o[d][e]*inv);
  }
}

extern "C" void kernel_launch(void* const* d_in, const int* in_sizes, int n_in,
                              void* d_out, int out_size, void* d_ws, size_t ws_size,
                              hipStream_t stream) {
  const float* seq  = (const float*)d_in[0];
  const float* nw   = (const float*)d_in[1];
  const float* wqkv = (const float*)d_in[2];
  const float* wout = (const float*)d_in[3];
  const float* pmem = (const float*)d_in[4];
  float* out0  = (float*)d_out;
  float* origv = out0 + (size_t)MROWS*ND;

  char* ws = (char*)d_ws;
  unsigned short* xbf   = (unsigned short*)(ws + 0);          // 16,777,216
  unsigned short* wqkvT = (unsigned short*)(ws + 16777216);   //  6,291,456
  unsigned short* woutT = (unsigned short*)(ws + 23068672);   //  2,097,152
  float*          cosT  = (float*)(ws + 25165824);            //    524,288
  float*          sinT  = (float*)(ws + 25690112);            //    524,288
  unsigned short* Qb    = (unsigned short*)(ws + 26214400);   // 16,777,216
  unsigned short* Kb    = (unsigned short*)(ws + 42991616);   // 17,301,504
  unsigned short* Vb    = (unsigned short*)(ws + 60293120);   // 17,301,504
  unsigned short* att   = (unsigned short*)(ws + 77594624);   // 16,777,216  (end ~94.4 MB)

  rope_table_k<<<dim3(512), dim3(256), 0, stream>>>(cosT, sinT);
  rmsnorm_k<<<dim3(MROWS), dim3(256), 0, stream>>>(seq, nw, xbf);
  tcast_k<<<dim3(NQKV/32, 1024/32), dim3(256), 0, stream>>>(wqkv, wqkvT, 1024, NQKV);
  tcast_k<<<dim3(1024/32, 1024/32), dim3(256), 0, stream>>>(wout, woutT, 1024, 1024);
  pmem_fill_k<<<dim3(1024), dim3(256), 0, stream>>>(pmem, Kb, Vb);
  gemm_qkv_k<<<dim3(NQKV/128, MROWS/128), dim3(256), 0, stream>>>(
      xbf, wqkvT, Qb, Kb, Vb, origv, cosT, sinT);
  attn_k<<<dim3(8, 16, 16), dim3(256), 0, stream>>>(Qb, Kb, Vb, att);
  gemm_out_k<<<dim3(1024/128, MROWS/128), dim3(256), 0, stream>>>(att, woutT, out0);
}

// Round 5
// 205.434 us; speedup vs baseline: 1.9463x; 1.4261x over previous
//
#include <hip/hip_runtime.h>
#include <hip/hip_bf16.h>
#include <stdint.h>

#define HEADS 16
#define DIMH 64
#define SEGL 512
#define NPM 16
#define NB 2
#define NS 4096
#define ND 1024
#define NW 8
#define NBW 16
#define KVLEN 528
#define NQKV 3072
#define MROWS 8192
#define RMS_EPS 1.1920928955078125e-07f

typedef __attribute__((ext_vector_type(8))) short bf16x8;
typedef __attribute__((ext_vector_type(4))) float f32x4;

union FragU { bf16x8 v; uint64_t q[2]; unsigned short u[8]; };

__device__ inline unsigned short f2bf(float x){
  __hip_bfloat16 b = __float2bfloat16(x);
  return __builtin_bit_cast(unsigned short, b);
}

__device__ inline f32x4 mfma16(bf16x8 a, bf16x8 b, f32x4 c){
  return __builtin_amdgcn_mfma_f32_16x16x32_bf16(a, b, c, 0, 0, 0);
}

// async global->LDS, 16B per lane; LDS dest = wave-uniform base + lane*16
__device__ __forceinline__ void gl_lds16(const unsigned short* g, unsigned short* l){
  __builtin_amdgcn_global_load_lds(
    (const __attribute__((address_space(1))) unsigned int*)g,
    (__attribute__((address_space(3))) unsigned int*)l, 16, 0, 0);
}

// stage one wave's 32 rows (16B/lane per inst) of A and B K-chunks (GEMM)
__device__ __forceinline__ void stage4(const unsigned short* gA, const unsigned short* gB,
                                       unsigned short* sA, unsigned short* sB, size_t row16){
  gl_lds16(gA,         sA);
  gl_lds16(gA + row16, sA + 512);
  gl_lds16(gB,         sB);
  gl_lds16(gB + row16, sB + 512);
}

// ---------------- rope table ----------------
__global__ void rope_table_k(float* __restrict__ cosT, float* __restrict__ sinT){
  int id = blockIdx.x*256 + threadIdx.x;
  if (id >= NS*32) return;
  int p = id & 31, s = id >> 5;
  float inv = powf(10000.0f, -(float)p * (1.0f/32.0f));
  float a = (float)s * inv;
  cosT[id] = cosf(a);
  sinT[id] = sinf(a);
}

// ---------------- rmsnorm + cast ----------------
__global__ __launch_bounds__(256) void rmsnorm_k(const float* __restrict__ seq, const float* __restrict__ nw,
                                                 unsigned short* __restrict__ xo){
  int r = blockIdx.x, t = threadIdx.x;
  const float4 v = ((const float4*)(seq + (size_t)r*ND))[t];
  float ss = v.x*v.x + v.y*v.y + v.z*v.z + v.w*v.w;
  #pragma unroll
  for (int off=32; off; off>>=1) ss += __shfl_xor(ss, off);
  __shared__ float red[4];
  if ((t&63)==0) red[t>>6] = ss;
  __syncthreads();
  float scale = rsqrtf((red[0]+red[1]+red[2]+red[3])*(1.0f/(float)ND) + RMS_EPS);
  const float4 w = ((const float4*)nw)[t];
  ushort4 o;
  o.x = f2bf(v.x*scale*w.x);
  o.y = f2bf(v.y*scale*w.y);
  o.z = f2bf(v.z*scale*w.z);
  o.w = f2bf(v.w*scale*w.w);
  ((ushort4*)xo)[(size_t)r*256 + t] = o;
}

// ---------------- transpose + cast weights ----------------
__global__ __launch_bounds__(256) void tcast_k(const float* __restrict__ in, unsigned short* __restrict__ out,
                                               int R, int C){
  __shared__ float tile[32][33];
  int c0 = blockIdx.x*32, r0 = blockIdx.y*32;
  int tx = threadIdx.x & 31, ty = threadIdx.x >> 5;
  #pragma unroll
  for (int i=0;i<4;i++) tile[ty+8*i][tx] = in[(size_t)(r0+ty+8*i)*C + c0+tx];
  __syncthreads();
  #pragma unroll
  for (int i=0;i<4;i++) out[(size_t)(c0+ty+8*i)*R + r0+tx] = f2bf(tile[tx][ty+8*i]);
}

// ---------------- pmem prefix fill ----------------
// K prefix stays [j][d]; V prefix goes to the TRANSPOSED global V buffer [d][j=528].
__global__ void pmem_fill_k(const float* __restrict__ pmem, unsigned short* __restrict__ Kb,
                            unsigned short* __restrict__ VbT){
  int id = blockIdx.x*256 + threadIdx.x;
  if (id >= NBW*HEADS*NPM*DIMH) return;
  int d = id & 63, j = (id>>6)&15, h = (id>>10)&15, bw = id>>14;
  size_t srcK = ((size_t)h*NPM + j)*DIMH + d;
  Kb[((size_t)(bw*HEADS+h)*KVLEN + j)*DIMH + d] = f2bf(pmem[srcK]);
  VbT[((size_t)(bw*HEADS+h)*DIMH + d)*KVLEN + j] = f2bf(pmem[(size_t)HEADS*NPM*DIMH + srcK]);
}

// ---------------- GEMM body (2-phase dbuf, unchanged structure) ----------------
// MODE 0: write f32 C. MODE 1: fused qkv epilogue (rope + scatter; V written TRANSPOSED).
template<int MODE>
__device__ __forceinline__ void gemm_body(const unsigned short* __restrict__ A,
    const unsigned short* __restrict__ Bt, float* __restrict__ Cf,
    unsigned short* __restrict__ Qb, unsigned short* __restrict__ Kb, unsigned short* __restrict__ VbT,
    float* __restrict__ origv, const float* __restrict__ cosT, const float* __restrict__ sinT,
    int M, int N, int K){
  __shared__ __align__(16) unsigned short As[2][4096];  // [buf][128][32]
  __shared__ __align__(16) unsigned short Bs[2][4096];
  int t = threadIdx.x; int lane = t&63; int wv = t>>6; int lr = lane&15; int lg = lane>>4;
  int wm = wv>>1, wn = wv&1;
  int m0 = blockIdx.y*128, n0 = blockIdx.x*128;

  f32x4 acc[4][4];
  f32x4 z = {0.f,0.f,0.f,0.f};
  #pragma unroll
  for (int i=0;i<4;i++)
    #pragma unroll
    for (int j=0;j<4;j++) acc[i][j] = z;

  const unsigned short* gA = A  + (size_t)(m0 + wv*32 + (lane>>2))*K + (lane&3)*8;
  const unsigned short* gB = Bt + (size_t)(n0 + wv*32 + (lane>>2))*K + (lane&3)*8;
  const size_t row16 = (size_t)16*K;

  int aoff[4], boff[4];
  #pragma unroll
  for (int i=0;i<4;i++){
    aoff[i] = (wm*64 + i*16 + lr)*64 + lg*16;
    boff[i] = (wn*64 + i*16 + lr)*64 + lg*16;
  }

  stage4(gA, gB, As[0] + wv*1024, Bs[0] + wv*1024, row16);
  __syncthreads();

  int cur = 0;
  for (int k0=0; k0<K; k0+=32){
    int nk = k0 + 32;
    if (nk < K)
      stage4(gA + nk, gB + nk, As[cur^1] + wv*1024, Bs[cur^1] + wv*1024, row16);
    const char* AsB = (const char*)As[cur];
    const char* BsB = (const char*)Bs[cur];
    bf16x8 af[4], bfr[4];
    #pragma unroll
    for (int i=0;i<4;i++){
      af[i]  = *(const bf16x8*)(AsB + aoff[i]);
      bfr[i] = *(const bf16x8*)(BsB + boff[i]);
    }
    #pragma unroll
    for (int i=0;i<4;i++)
      #pragma unroll
      for (int j=0;j<4;j++)
        acc[i][j] = mfma16(af[i], bfr[j], acc[i][j]);
    __syncthreads();
    cur ^= 1;
  }

  #pragma unroll
  for (int i=0;i<4;i++){
    #pragma unroll
    for (int j=0;j<4;j++){
      if constexpr (MODE == 0){
        #pragma unroll
        for (int e=0;e<4;e++){
          int row = m0 + wm*64 + i*16 + lg*4 + e;
          int col = n0 + wn*64 + j*16 + lr;
          Cf[(size_t)row*N + col] = acc[i][j][e];
        }
      } else {
        int col  = n0 + wn*64 + j*16 + lr;
        int rowb = m0 + wm*64 + i*16 + lg*4;
        if (col < 2048){
          #pragma unroll
          for (int e=0;e<4;e++){
            int row = rowb + e;
            float val = acc[i][j][e];
            float partner = __shfl_xor(val, 1);
            int s = row&4095;
            int w = s>>9, ii = s&511, bwi = (row>>12)*8 + w;
            int hh = (col>>6)&15, dh = col&63;
            int fp = dh>>1;
            float cs = cosT[s*32+fp], sn = sinT[s*32+fp];
            float rot = (col&1) ? fmaf(val,cs, partner*sn) : fmaf(val,cs, -partner*sn);
            if (col < 1024) Qb[((size_t)(bwi*HEADS+hh)*SEGL + ii)*DIMH + dh] = f2bf(rot);
            else            Kb[((size_t)(bwi*HEADS+hh)*KVLEN + NPM + ii)*DIMH + dh] = f2bf(rot);
          }
        } else {
          int b = rowb>>12, s = rowb&4095;
          int w = s>>9, ii = s&511, bwi = b*8 + w;
          int hh = (col>>6)&15, dh = col&63;
          ushort4 pk;
          pk.x = f2bf(acc[i][j][0]); pk.y = f2bf(acc[i][j][1]);
          pk.z = f2bf(acc[i][j][2]); pk.w = f2bf(acc[i][j][3]);
          // V transposed: [bwh][d][j], ii is 4-aligned -> 8B-aligned vector store
          *(ushort4*)&VbT[((size_t)(bwi*HEADS+hh)*DIMH + dh)*KVLEN + NPM + ii] = pk;
          #pragma unroll
          for (int e=0;e<4;e++)
            origv[((size_t)(b*HEADS+hh)*NS + s + e)*DIMH + dh] = acc[i][j][e];
        }
      }
    }
  }
}

__global__ __launch_bounds__(256) void gemm_qkv_k(const unsigned short* __restrict__ A,
    const unsigned short* __restrict__ Bt,
    unsigned short* __restrict__ Qb, unsigned short* __restrict__ Kb, unsigned short* __restrict__ VbT,
    float* __restrict__ origv, const float* __restrict__ cosT, const float* __restrict__ sinT){
  gemm_body<1>(A, Bt, nullptr, Qb, Kb, VbT, origv, cosT, sinT, MROWS, NQKV, 1024);
}

__global__ __launch_bounds__(256) void gemm_out_k(const unsigned short* __restrict__ A,
    const unsigned short* __restrict__ Bt, float* __restrict__ Cf){
  gemm_body<0>(A, Bt, Cf, nullptr, nullptr, nullptr, nullptr, nullptr, nullptr, MROWS, 1024, 1024);
}

// ---------------- attention (swapped-QK, V^T in global, 2-phase dbuf) ----------------
// Block: 4 waves, 128 q-rows (wave owns 32 = 2 x 16-row frags). KV tile = 64.
// K LDS: [64 j][128B], XOR-swizzled (byte ^= (row&7)<<4) via pre-swizzled gload_lds source.
// V LDS: [64 d][128B] slice of global V^T (columns j0..j0+63), SAME swizzle scheme.
// Both fragments read as ds_read_b64 pairs at XOR'd offsets (mirror of GEMM pattern).
__global__ __launch_bounds__(256) void attn_k(const unsigned short* __restrict__ Qb,
    const unsigned short* __restrict__ Kb, const unsigned short* __restrict__ VbT,
    unsigned short* __restrict__ att){
  int qt = blockIdx.x, h = blockIdx.y, bw = blockIdx.z;
  int t = threadIdx.x, lane = t&63, wv = t>>6, lr = lane&15, lg = lane>>4;
  __shared__ __align__(16) unsigned short Ks[2][4096];
  __shared__ __align__(16) unsigned short Vs[2][4096];

  const unsigned short* Kbase = Kb  + (size_t)(bw*HEADS+h)*KVLEN*DIMH;
  const unsigned short* Vtb   = VbT + (size_t)(bw*HEADS+h)*DIMH*KVLEN;  // row stride KVLEN (in j)

  // ---- Q fragments (B-operand): q-row = qt*128 + wv*32 + ifr*16 + lr ----
  bf16x8 qf[2][2];  // [ifr][kh]; k-map: q[0] d=kh*32+lg*4+{0..3}, q[1] +16
  #pragma unroll
  for (int ifr=0; ifr<2; ++ifr){
    const unsigned short* Qrow = Qb + ((size_t)((bw*HEADS+h)*SEGL) + qt*128 + wv*32 + ifr*16 + lr)*DIMH;
    #pragma unroll
    for (int kh=0; kh<2; ++kh){
      FragU f;
      f.q[0] = *(const uint64_t*)(Qrow + kh*32 + lg*4);
      f.q[1] = *(const uint64_t*)(Qrow + kh*32 + 16 + lg*4);
      qf[ifr][kh] = f.v;
    }
  }

  // ---- staging per-lane precompute: row rl, swizzled 16B-chunk offset ----
  int rls[2], xsw[2];
  #pragma unroll
  for (int k2=0;k2<2;k2++){
    rls[k2] = wv*16 + k2*8 + (lane>>3);
    xsw[k2] = ((lane&7)*16) ^ ((rls[k2]&7)<<4);
  }

  // K rows clamp (duplicates masked later); V last-tile chunks clamp to valid 32B
  // (clamped chunks only feed masked j>=528 columns; &31 keeps live chunks intact).
  #define STAGE_KV(buf, j0_) do { \
    int xm_ = ((j0_) == 512) ? 31 : 127; \
    _Pragma("unroll") \
    for (int k2=0;k2<2;k2++){ \
      int jr = (j0_) + rls[k2]; if (jr>527) jr=527; \
      gl_lds16((const unsigned short*)((const char*)Kbase + (size_t)jr*128 + xsw[k2]), \
               Ks[buf] + wv*1024 + k2*512); \
      gl_lds16((const unsigned short*)((const char*)Vtb + (size_t)rls[k2]*(KVLEN*2) + (size_t)(j0_)*2 + (xsw[k2] & xm_)), \
               Vs[buf] + wv*1024 + k2*512); \
    } \
  } while(0)

  const float NEG = -3.0e38f;
  float m[2]  = {NEG, NEG};
  float lsum[2] = {0.f, 0.f};
  f32x4 o[4][2];  // [df][ifr]
  f32x4 z = {0.f,0.f,0.f,0.f};
  #pragma unroll
  for (int df=0; df<4; ++df){ o[df][0]=z; o[df][1]=z; }

  int ntiles = (qt*128 + 207)>>6; if (ntiles>9) ntiles=9;
  int swzK = (lr&7)<<4;

  STAGE_KV(0, 0);
  __syncthreads();

  int cur = 0;
  for (int jt=0; jt<ntiles; ++jt){
    int j0 = jt*64;
    if (jt+1 < ntiles) STAGE_KV(cur^1, j0+64);

    // ---- QK^T (swapped: A=K, B=Q) -> s[ifr][jf]: row=kv j (lg*4+e), col=q (lr) ----
    const char* KsB = (const char*)Ks[cur];
    f32x4 s[2][4];
    #pragma unroll
    for (int ifr=0; ifr<2; ++ifr)
      #pragma unroll
      for (int jf=0; jf<4; ++jf) s[ifr][jf] = z;
    #pragma unroll
    for (int jf=0; jf<4; ++jf){
      int rowb = (jf*16 + lr)*128;
      #pragma unroll
      for (int kh=0; kh<2; ++kh){
        FragU kf;
        kf.q[0] = *(const uint64_t*)(KsB + rowb + ((kh*64      + lg*8) ^ swzK));
        kf.q[1] = *(const uint64_t*)(KsB + rowb + ((kh*64 + 32 + lg*8) ^ swzK));
        s[0][jf] = mfma16(kf.v, qf[0][kh], s[0][jf]);
        s[1][jf] = mfma16(kf.v, qf[1][kh], s[1][jf]);
      }
    }

    // ---- mask + online softmax (q-row lives in lane lr; reduce over lg via xor16/32) ----
    float alpha[2];
    #pragma unroll
    for (int ifr=0; ifr<2; ++ifr){
      int iglob = qt*128 + wv*32 + ifr*16 + lr;
      float mt = NEG;
      #pragma unroll
      for (int jf=0; jf<4; ++jf){
        #pragma unroll
        for (int e=0;e<4;e++){
          int jl = j0 + jf*16 + lg*4 + e;
          bool ok = (jl < KVLEN) && (jl - NPM <= iglob);
          float v = ok ? s[ifr][jf][e]*0.125f : NEG;
          s[ifr][jf][e] = v;
          mt = fmaxf(mt, v);
        }
      }
      mt = fmaxf(mt, __shfl_xor(mt, 16));
      mt = fmaxf(mt, __shfl_xor(mt, 32));
      float mn = fmaxf(m[ifr], mt);
      alpha[ifr] = __expf(m[ifr]-mn);
      m[ifr] = mn;
      float ps = 0.f;
      #pragma unroll
      for (int jf=0; jf<4; ++jf){
        #pragma unroll
        for (int e=0;e<4;e++){
          float p = __expf(s[ifr][jf][e] - mn);
          s[ifr][jf][e] = p;
          ps += p;
        }
      }
      ps += __shfl_xor(ps, 16);
      ps += __shfl_xor(ps, 32);
      lsum[ifr] = lsum[ifr]*alpha[ifr] + ps;
    }

    // ---- P pack (lane-local; A-operand row=lr=q-row, k=kv split-map) ----
    bf16x8 pa[2][2];  // [ifr][kh]
    #pragma unroll
    for (int ifr=0; ifr<2; ++ifr){
      #pragma unroll
      for (int kh=0; kh<2; ++kh){
        FragU f;
        #pragma unroll
        for (int e=0;e<4;e++){
          f.u[e]   = f2bf(s[ifr][2*kh  ][e]);
          f.u[4+e] = f2bf(s[ifr][2*kh+1][e]);
        }
        pa[ifr][kh] = f.v;
      }
    }

    // ---- rescale o (o row = q-row lg*4+e; alpha lives at lane lr=q-row -> shfl) ----
    #pragma unroll
    for (int ifr=0; ifr<2; ++ifr){
      float ae[4];
      #pragma unroll
      for (int e=0;e<4;e++) ae[e] = __shfl(alpha[ifr], lg*4+e, 16);
      #pragma unroll
      for (int df=0; df<4; ++df)
        #pragma unroll
        for (int e=0;e<4;e++) o[df][ifr][e] *= ae[e];
    }

    // ---- PV: A=P (in-reg), B=V^T fragment from swizzled Vs (rows = d) ----
    const char* VsB = (const char*)Vs[cur];
    #pragma unroll
    for (int df=0; df<4; ++df){
      int vrow = (df*16 + lr)*128;
      FragU v0, v1;
      v0.q[0] = *(const uint64_t*)(VsB + vrow + ((      lg*8) ^ swzK));
      v0.q[1] = *(const uint64_t*)(VsB + vrow + ((32  + lg*8) ^ swzK));
      v1.q[0] = *(const uint64_t*)(VsB + vrow + ((64  + lg*8) ^ swzK));
      v1.q[1] = *(const uint64_t*)(VsB + vrow + ((96  + lg*8) ^ swzK));
      o[df][0] = mfma16(pa[0][0], v0.v, o[df][0]);
      o[df][0] = mfma16(pa[0][1], v1.v, o[df][0]);
      o[df][1] = mfma16(pa[1][0], v0.v, o[df][1]);
      o[df][1] = mfma16(pa[1][1], v1.v, o[df][1]);
    }

    __syncthreads();
    cur ^= 1;
  }

  // ---- epilogue: o row = q-row (lg*4+e), col = d (df*16+lr) ----
  #pragma unroll
  for (int ifr=0; ifr<2; ++ifr){
    float inv = 1.0f / lsum[ifr];
    float il[4];
    #pragma unroll
    for (int e=0;e<4;e++) il[e] = __shfl(inv, lg*4+e, 16);
    #pragma unroll
    for (int e=0;e<4;e++){
      int row = bw*SEGL + qt*128 + wv*32 + ifr*16 + lg*4 + e;
      #pragma unroll
      for (int df=0; df<4; ++df)
        att[(size_t)row*1024 + h*64 + df*16 + lr] = f2bf(o[df][ifr][e]*il[e]);
    }
  }
  #undef STAGE_KV
}

extern "C" void kernel_launch(void* const* d_in, const int* in_sizes, int n_in,
                              void* d_out, int out_size, void* d_ws, size_t ws_size,
                              hipStream_t stream) {
  const float* seq  = (const float*)d_in[0];
  const float* nw   = (const float*)d_in[1];
  const float* wqkv = (const float*)d_in[2];
  const float* wout = (const float*)d_in[3];
  const float* pmem = (const float*)d_in[4];
  float* out0  = (float*)d_out;
  float* origv = out0 + (size_t)MROWS*ND;

  char* ws = (char*)d_ws;
  unsigned short* xbf   = (unsigned short*)(ws + 0);          // 16,777,216
  unsigned short* wqkvT = (unsigned short*)(ws + 16777216);   //  6,291,456
  unsigned short* woutT = (unsigned short*)(ws + 23068672);   //  2,097,152
  float*          cosT  = (float*)(ws + 25165824);            //    524,288
  float*          sinT  = (float*)(ws + 25690112);            //    524,288
  unsigned short* Qb    = (unsigned short*)(ws + 26214400);   // 16,777,216
  unsigned short* Kb    = (unsigned short*)(ws + 42991616);   // 17,301,504
  unsigned short* VbT   = (unsigned short*)(ws + 60293120);   // 17,301,504 (transposed [bwh][64][528])
  unsigned short* att   = (unsigned short*)(ws + 77594624);   // 16,777,216  (end ~94.4 MB)

  rope_table_k<<<dim3(512), dim3(256), 0, stream>>>(cosT, sinT);
  rmsnorm_k<<<dim3(MROWS), dim3(256), 0, stream>>>(seq, nw, xbf);
  tcast_k<<<dim3(NQKV/32, 1024/32), dim3(256), 0, stream>>>(wqkv, wqkvT, 1024, NQKV);
  tcast_k<<<dim3(1024/32, 1024/32), dim3(256), 0, stream>>>(wout, woutT, 1024, 1024);
  pmem_fill_k<<<dim3(1024), dim3(256), 0, stream>>>(pmem, Kb, VbT);
  gemm_qkv_k<<<dim3(NQKV/128, MROWS/128), dim3(256), 0, stream>>>(
      xbf, wqkvT, Qb, Kb, VbT, origv, cosT, sinT);
  attn_k<<<dim3(4, 16, 16), dim3(256), 0, stream>>>(Qb, Kb, VbT, att);
  gemm_out_k<<<dim3(1024/128, MROWS/128), dim3(256), 0, stream>>>(att, woutT, out0);
}